// Round 7
// baseline (601.574 us; speedup 1.0000x reference)
//
#include <hip/hip_runtime.h>

#define B_ 4
#define T_ 448
#define U_ 448
#define SKS_ 96
#define BKS_ 32
#define H_ 96
#define V_ 128

typedef __attribute__((ext_vector_type(8))) short bf16x8;
typedef __attribute__((ext_vector_type(4))) float f32x4;
typedef __attribute__((ext_vector_type(4))) int i32x4;

__device__ __forceinline__ unsigned short f2bf(float f) {
    unsigned int u = __float_as_uint(f);
    u += 0x7fffu + ((u >> 16) & 1u);   // round-to-nearest-even
    return (unsigned short)(u >> 16);
}
__device__ __forceinline__ float bf2f(unsigned short h) {
    return __uint_as_float(((unsigned int)h) << 16);
}

// ---------------------------------------------------------------------------
// Prep kernel (unchanged):
//   blocks [0, B*T)        : sh[b,t,h] = s[b,t,:] . W_sh[h,:] + b_sh[h]        -> bf16 ws
//   blocks [B*T, 2*B*T)    : rbh[b,u,h] = relu(b[b,u,:] . W_bh[h,:] + b_bh[h]) -> bf16 ws
//   blocks [2*B*T, +12)    : repack W_out (f32 [128][96]) -> bf16 ws [k8][n][8]
// ---------------------------------------------------------------------------
__global__ __launch_bounds__(128) void prep_kernel(
    const float* __restrict__ s, const float* __restrict__ b,
    const float* __restrict__ W_sh, const float* __restrict__ b_sh,
    const float* __restrict__ W_bh, const float* __restrict__ b_bh,
    const float* __restrict__ W_out,
    unsigned short* __restrict__ sh_ws,
    unsigned short* __restrict__ rbh_ws,
    unsigned short* __restrict__ w_ws)
{
    const int blk = blockIdx.x;
    const int tid = threadIdx.x;

    if (blk < B_ * T_) {
        __shared__ float row[SKS_];
        if (tid < SKS_) row[tid] = s[(size_t)blk * SKS_ + tid];
        __syncthreads();
        if (tid < H_) {
            const float* w = W_sh + (size_t)tid * SKS_;
            float acc = b_sh[tid];
            #pragma unroll
            for (int k = 0; k < SKS_; k += 4) {
                acc += row[k] * w[k] + row[k + 1] * w[k + 1]
                     + row[k + 2] * w[k + 2] + row[k + 3] * w[k + 3];
            }
            sh_ws[(size_t)blk * H_ + tid] = f2bf(acc);
        }
    } else if (blk < 2 * B_ * T_) {
        const int r = blk - B_ * T_;
        __shared__ float row2[BKS_];
        if (tid < BKS_) row2[tid] = b[(size_t)r * BKS_ + tid];
        __syncthreads();
        if (tid < H_) {
            const float* w = W_bh + (size_t)tid * BKS_;
            float acc = b_bh[tid];
            #pragma unroll
            for (int k = 0; k < BKS_; k += 4) {
                acc += row2[k] * w[k] + row2[k + 1] * w[k + 1]
                     + row2[k + 2] * w[k + 2] + row2[k + 3] * w[k + 3];
            }
            acc = fmaxf(acc, 0.0f);
            rbh_ws[(size_t)r * H_ + tid] = f2bf(acc);
        }
    } else {
        // W_out repack: c = k8*128 + n ; src = W_out[n][k8*8 .. +8] ; dst 16B chunk c
        const int c = (blk - 2 * B_ * T_) * 128 + tid;   // 0..1535
        const int k8 = c >> 7;
        const int n  = c & 127;
        const float* src = W_out + (size_t)n * H_ + k8 * 8;
        unsigned short tmp[8];
        #pragma unroll
        for (int j = 0; j < 8; j++) tmp[j] = f2bf(src[j]);
        i32x4 v;
        v.x = (int)((unsigned)tmp[0] | ((unsigned)tmp[1] << 16));
        v.y = (int)((unsigned)tmp[2] | ((unsigned)tmp[3] << 16));
        v.z = (int)((unsigned)tmp[4] | ((unsigned)tmp[5] << 16));
        v.w = (int)((unsigned)tmp[6] | ((unsigned)tmp[7] << 16));
        ((i32x4*)w_ws)[c] = v;
    }
}

// ---------------------------------------------------------------------------
// PERSISTENT-TILE joiner. 896 blocks = 28 u-tiles x 32 workers.
// Worker k: bb = k>>3, t4 range = (k&7)*14 + [0,14)  (14 | 112, so one bb).
// Per block: stage W (24 KB) to LDS ONCE; rbh fragments in REGISTERS (loaded
// once); loop 14 (b,t)-tiles with ZERO barriers: shf prefetch -> MFMA ->
// softmax -> per-wave-PRIVATE LDS transpose (4 KB each, 2 half-passes,
// XOR-swizzled) -> contiguous 256-B-segment stores.
// LDS = 24 KB W + 16 KB Ol = 40 KB -> 4 blocks/CU.
// ---------------------------------------------------------------------------
__global__ __launch_bounds__(256, 4) void joiner_kernel(
    const unsigned short* __restrict__ sh_ws,
    const unsigned short* __restrict__ rbh_ws,
    const unsigned short* __restrict__ w_ws,
    const float* __restrict__ b_out,
    float* __restrict__ out)
{
    __shared__ __align__(16) unsigned char SMEM[24576 + 16384];   // 40 KB
    unsigned short* Wl = (unsigned short*)SMEM;                   // [12*128*8]
    f32x4* Ol4 = (f32x4*)(SMEM + 24576);                          // [4][256]

    const int tid    = threadIdx.x;
    const int u_tile = blockIdx.x >> 5;        // 0..27
    const int k      = blockIdx.x & 31;        // 0..31
    const int bb     = k >> 3;                 // 0..3
    const int tbase  = (k & 7) * 14;           // t4 base; t4 = tbase + i
    const int u0     = u_tile * 16;

    // ---- stage W_out fragments once (contiguous 16B chunks) ----
    {
        const i32x4* src = (const i32x4*)w_ws;
        i32x4* dst = (i32x4*)Wl;
        #pragma unroll
        for (int i = 0; i < 6; i++) {
            const int c = i * 256 + tid;
            dst[c] = src[c];
        }
    }
    __syncthreads();

    const int wave = tid >> 6;
    const int lane = tid & 63;
    const int n    = lane & 15;   // u-within-tile; v_local for W frag
    const int q    = lane >> 4;   // k-chunk; v-subquad of output v index

    // ---- rbh fragments: fixed per block, load once into registers ----
    const unsigned short* rbrow = rbh_ws + ((size_t)(bb * U_ + u0 + n)) * H_;
    bf16x8 rb[3];
    #pragma unroll
    for (int ks = 0; ks < 3; ks++)
        rb[ks] = *(const bf16x8*)(rbrow + ks * 32 + q * 8);

    f32x4* Olw = Ol4 + wave * 256;   // private 4 KB

    // ---- prefetch shf for i = 0 ----
    bf16x8 shf[3];
    {
        const int t = (tbase + 0) * 4 + wave;
        const unsigned short* shrow = sh_ws + ((size_t)(bb * T_ + t)) * H_;
        #pragma unroll
        for (int ks = 0; ks < 3; ks++)
            shf[ks] = *(const bf16x8*)(shrow + ks * 32 + q * 8);
    }

    #pragma unroll 1
    for (int i = 0; i < 14; ++i) {
        const int t = (tbase + i) * 4 + wave;

        f32x4 acc[8];
        #pragma unroll
        for (int nt = 0; nt < 8; nt++) acc[nt] = (f32x4){0.f, 0.f, 0.f, 0.f};

        #pragma unroll
        for (int ks = 0; ks < 3; ks++) {
            bf16x8 af;
            #pragma unroll
            for (int j = 0; j < 8; j++) {
                const float z = bf2f((unsigned short)shf[ks][j]) *
                                bf2f((unsigned short)rb[ks][j]);
                af[j] = (short)f2bf(z);
            }
            #pragma unroll
            for (int nt = 0; nt < 8; nt++) {
                const bf16x8 wfr = *(const bf16x8*)(Wl +
                    ((size_t)((ks * 4 + q) * 128 + nt * 16 + n)) * 8);
                // A = W tile (M = v), B = z tile (N = u)
                acc[nt] = __builtin_amdgcn_mfma_f32_16x16x32_bf16(wfr, af, acc[nt], 0, 0, 0);
            }
        }

        // ---- prefetch next iteration's shf (hidden under epilogue) ----
        bf16x8 shn[3];
        {
            const int inx = (i < 13) ? (i + 1) : i;
            const int tn  = (tbase + inx) * 4 + wave;
            const unsigned short* shrow = sh_ws + ((size_t)(bb * T_ + tn)) * H_;
            #pragma unroll
            for (int ks = 0; ks < 3; ks++)
                shn[ks] = *(const bf16x8*)(shrow + ks * 32 + q * 8);
        }

        // ---- epilogue: bias + log_softmax; one output row (u = u0+n) per lane
        #pragma unroll
        for (int nt = 0; nt < 8; nt++) {
            const f32x4 bias4 = *(const f32x4*)(b_out + nt * 16 + q * 4);
            acc[nt] += bias4;
        }

        float mx[8];
        #pragma unroll
        for (int nt = 0; nt < 8; nt++)
            mx[nt] = fmaxf(fmaxf(acc[nt][0], acc[nt][1]),
                           fmaxf(acc[nt][2], acc[nt][3]));
        float m = fmaxf(fmaxf(fmaxf(mx[0], mx[1]), fmaxf(mx[2], mx[3])),
                        fmaxf(fmaxf(mx[4], mx[5]), fmaxf(mx[6], mx[7])));
        m = fmaxf(m, __shfl_xor(m, 16, 64));
        m = fmaxf(m, __shfl_xor(m, 32, 64));

        float s0 = 0.f, s1 = 0.f, s2 = 0.f, s3 = 0.f;
        #pragma unroll
        for (int nt = 0; nt < 8; nt++) {
            s0 += __expf(acc[nt][0] - m);
            s1 += __expf(acc[nt][1] - m);
            s2 += __expf(acc[nt][2] - m);
            s3 += __expf(acc[nt][3] - m);
        }
        float ssum = (s0 + s1) + (s2 + s3);
        ssum += __shfl_xor(ssum, 16, 64);
        ssum += __shfl_xor(ssum, 32, 64);

        const float logz = m + __logf(ssum);

        // ---- per-wave private transpose, two half-passes (no barriers) ----
        // write chunk L = n*16 + w4*4 + q, phys P = L ^ ((L>>4)&7): conflict-free.
        // read  chunk c = ii*64 + lane, same swizzle: <=2-way.
        const size_t orow0 = (size_t)(bb * T_ + t) * U_ + u0;
        #pragma unroll
        for (int p = 0; p < 2; p++) {
            #pragma unroll
            for (int w4 = 0; w4 < 4; w4++) {
                const int nt = p * 4 + w4;
                const int L  = (n << 4) + (w4 << 2) + q;
                const int P  = L ^ ((L >> 4) & 7);
                Olw[P] = acc[nt] - logz;
            }
            #pragma unroll
            for (int ii = 0; ii < 4; ii++) {
                const int c = (ii << 6) + lane;
                const int P = c ^ ((c >> 4) & 7);
                const f32x4 v = Olw[P];
                const int u = c >> 4;      // 0..15
                const int j = c & 15;      // v-chunk within half
                *(f32x4*)(out + (orow0 + u) * V_ + p * 64 + j * 4) = v;
            }
        }

        // rotate prefetched shf
        #pragma unroll
        for (int ks = 0; ks < 3; ks++) shf[ks] = shn[ks];
    }
}

extern "C" void kernel_launch(void* const* d_in, const int* in_sizes, int n_in,
                              void* d_out, int out_size, void* d_ws, size_t ws_size,
                              hipStream_t stream)
{
    const float* s     = (const float*)d_in[0];
    const float* b     = (const float*)d_in[1];
    const float* W_sh  = (const float*)d_in[2];
    const float* b_sh  = (const float*)d_in[3];
    const float* W_bh  = (const float*)d_in[4];
    const float* b_bh  = (const float*)d_in[5];
    const float* W_out = (const float*)d_in[6];
    const float* b_out = (const float*)d_in[7];
    float* out = (float*)d_out;

    unsigned short* sh_ws  = (unsigned short*)d_ws;
    unsigned short* rbh_ws = sh_ws + (size_t)B_ * T_ * H_;    // +344064 B
    unsigned short* w_ws   = rbh_ws + (size_t)B_ * U_ * H_;   // +344064 B (16B aligned)

    prep_kernel<<<2 * B_ * T_ + 12, 128, 0, stream>>>(
        s, b, W_sh, b_sh, W_bh, b_bh, W_out, sh_ws, rbh_ws, w_ws);

    joiner_kernel<<<dim3(28 * 32), 256, 0, stream>>>(
        sh_ws, rbh_ws, w_ws, b_out, out);
}

// Round 9
// 435.828 us; speedup vs baseline: 1.3803x; 1.3803x over previous
//
#include <hip/hip_runtime.h>

#define B_ 4
#define T_ 448
#define U_ 448
#define SKS_ 96
#define BKS_ 32
#define H_ 96
#define V_ 128

typedef __attribute__((ext_vector_type(8))) short bf16x8;
typedef __attribute__((ext_vector_type(4))) float f32x4;
typedef __attribute__((ext_vector_type(4))) int i32x4;

__device__ __forceinline__ unsigned short f2bf(float f) {
    unsigned int u = __float_as_uint(f);
    u += 0x7fffu + ((u >> 16) & 1u);   // round-to-nearest-even
    return (unsigned short)(u >> 16);
}
__device__ __forceinline__ float bf2f(unsigned short h) {
    return __uint_as_float(((unsigned int)h) << 16);
}

// ---------------------------------------------------------------------------
// Prep kernel (unchanged):
//   blocks [0, B*T)        : sh[b,t,h] = s[b,t,:] . W_sh[h,:] + b_sh[h]        -> bf16 ws
//   blocks [B*T, 2*B*T)    : rbh[b,u,h] = relu(b[b,u,:] . W_bh[h,:] + b_bh[h]) -> bf16 ws
//   blocks [2*B*T, +12)    : repack W_out (f32 [128][96]) -> bf16 ws [k8][n][8]
// ---------------------------------------------------------------------------
__global__ __launch_bounds__(128) void prep_kernel(
    const float* __restrict__ s, const float* __restrict__ b,
    const float* __restrict__ W_sh, const float* __restrict__ b_sh,
    const float* __restrict__ W_bh, const float* __restrict__ b_bh,
    const float* __restrict__ W_out,
    unsigned short* __restrict__ sh_ws,
    unsigned short* __restrict__ rbh_ws,
    unsigned short* __restrict__ w_ws)
{
    const int blk = blockIdx.x;
    const int tid = threadIdx.x;

    if (blk < B_ * T_) {
        __shared__ float row[SKS_];
        if (tid < SKS_) row[tid] = s[(size_t)blk * SKS_ + tid];
        __syncthreads();
        if (tid < H_) {
            const float* w = W_sh + (size_t)tid * SKS_;
            float acc = b_sh[tid];
            #pragma unroll
            for (int k = 0; k < SKS_; k += 4) {
                acc += row[k] * w[k] + row[k + 1] * w[k + 1]
                     + row[k + 2] * w[k + 2] + row[k + 3] * w[k + 3];
            }
            sh_ws[(size_t)blk * H_ + tid] = f2bf(acc);
        }
    } else if (blk < 2 * B_ * T_) {
        const int r = blk - B_ * T_;
        __shared__ float row2[BKS_];
        if (tid < BKS_) row2[tid] = b[(size_t)r * BKS_ + tid];
        __syncthreads();
        if (tid < H_) {
            const float* w = W_bh + (size_t)tid * BKS_;
            float acc = b_bh[tid];
            #pragma unroll
            for (int k = 0; k < BKS_; k += 4) {
                acc += row2[k] * w[k] + row2[k + 1] * w[k + 1]
                     + row2[k + 2] * w[k + 2] + row2[k + 3] * w[k + 3];
            }
            acc = fmaxf(acc, 0.0f);
            rbh_ws[(size_t)r * H_ + tid] = f2bf(acc);
        }
    } else {
        // W_out repack: c = k8*128 + n ; src = W_out[n][k8*8 .. +8] ; dst 16B chunk c
        const int c = (blk - 2 * B_ * T_) * 128 + tid;   // 0..1535
        const int k8 = c >> 7;
        const int n  = c & 127;
        const float* src = W_out + (size_t)n * H_ + k8 * 8;
        unsigned short tmp[8];
        #pragma unroll
        for (int j = 0; j < 8; j++) tmp[j] = f2bf(src[j]);
        i32x4 v;
        v.x = (int)((unsigned)tmp[0] | ((unsigned)tmp[1] << 16));
        v.y = (int)((unsigned)tmp[2] | ((unsigned)tmp[3] << 16));
        v.z = (int)((unsigned)tmp[4] | ((unsigned)tmp[5] << 16));
        v.w = (int)((unsigned)tmp[6] | ((unsigned)tmp[7] << 16));
        ((i32x4*)w_ws)[c] = v;
    }
}

// ---------------------------------------------------------------------------
// PERSISTENT-TILE joiner, v2. 1792 blocks = 28 u-tiles x 64 workers.
// Worker k (0..63): bb = k>>4, t4 range = (k&15)*7 + [0,7)  (7*16 = 112 = T_/4,
// so each worker stays in one bb). 1792/256 = exactly 7 blocks per CU.
// Per block: stage W (24 KB) to LDS ONCE; rbh fragments in REGISTERS; loop 7
// (b,t)-tiles with ZERO steady-state barriers: shf prefetch -> MFMA ->
// softmax -> per-wave-PRIVATE LDS transpose (4 KB, 2 half-passes, XOR-swizzle)
// -> contiguous 256-B-segment stores.
// LDS = 24 KB W + 16 KB Ol = 40 KB -> 4 blocks/CU.
// R7 lesson: __launch_bounds__(256,4) capped VGPRs at 64 -> massive scratch
// spill (FETCH_SIZE 607 MB). Use (256,2): 256-VGPR budget, demand ~100, no
// spill; LDS already limits to 4 blocks/CU so no occupancy loss.
// ---------------------------------------------------------------------------
__global__ __launch_bounds__(256, 2) void joiner_kernel(
    const unsigned short* __restrict__ sh_ws,
    const unsigned short* __restrict__ rbh_ws,
    const unsigned short* __restrict__ w_ws,
    const float* __restrict__ b_out,
    float* __restrict__ out)
{
    __shared__ __align__(16) unsigned char SMEM[24576 + 16384];   // 40 KB
    unsigned short* Wl = (unsigned short*)SMEM;                   // [12*128*8]
    f32x4* Ol4 = (f32x4*)(SMEM + 24576);                          // [4][256]

    const int tid    = threadIdx.x;
    const int u_tile = blockIdx.x >> 6;        // 0..27
    const int k      = blockIdx.x & 63;        // 0..63
    const int bb     = k >> 4;                 // 0..3
    const int tbase  = (k & 15) * 7;           // t4 base; t4 = tbase + i
    const int u0     = u_tile * 16;

    // ---- stage W_out fragments once (contiguous 16B chunks) ----
    {
        const i32x4* src = (const i32x4*)w_ws;
        i32x4* dst = (i32x4*)Wl;
        #pragma unroll
        for (int i = 0; i < 6; i++) {
            const int c = i * 256 + tid;
            dst[c] = src[c];
        }
    }
    __syncthreads();

    const int wave = tid >> 6;
    const int lane = tid & 63;
    const int n    = lane & 15;   // u-within-tile; v_local for W frag
    const int q    = lane >> 4;   // k-chunk; v-subquad of output v index

    // ---- rbh fragments: fixed per block, load once into registers ----
    const unsigned short* rbrow = rbh_ws + ((size_t)(bb * U_ + u0 + n)) * H_;
    bf16x8 rb[3];
    #pragma unroll
    for (int ks = 0; ks < 3; ks++)
        rb[ks] = *(const bf16x8*)(rbrow + ks * 32 + q * 8);

    f32x4* Olw = Ol4 + wave * 256;   // private 4 KB

    // ---- prefetch shf for i = 0 ----
    bf16x8 shf[3];
    {
        const int t = (tbase + 0) * 4 + wave;
        const unsigned short* shrow = sh_ws + ((size_t)(bb * T_ + t)) * H_;
        #pragma unroll
        for (int ks = 0; ks < 3; ks++)
            shf[ks] = *(const bf16x8*)(shrow + ks * 32 + q * 8);
    }

    #pragma unroll 1
    for (int i = 0; i < 7; ++i) {
        const int t = (tbase + i) * 4 + wave;

        f32x4 acc[8];
        #pragma unroll
        for (int nt = 0; nt < 8; nt++) acc[nt] = (f32x4){0.f, 0.f, 0.f, 0.f};

        #pragma unroll
        for (int ks = 0; ks < 3; ks++) {
            bf16x8 af;
            #pragma unroll
            for (int j = 0; j < 8; j++) {
                const float z = bf2f((unsigned short)shf[ks][j]) *
                                bf2f((unsigned short)rb[ks][j]);
                af[j] = (short)f2bf(z);
            }
            #pragma unroll
            for (int nt = 0; nt < 8; nt++) {
                const bf16x8 wfr = *(const bf16x8*)(Wl +
                    ((size_t)((ks * 4 + q) * 128 + nt * 16 + n)) * 8);
                // A = W tile (M = v), B = z tile (N = u)
                acc[nt] = __builtin_amdgcn_mfma_f32_16x16x32_bf16(wfr, af, acc[nt], 0, 0, 0);
            }
        }

        // ---- prefetch next iteration's shf (hidden under epilogue) ----
        bf16x8 shn[3];
        {
            const int inx = (i < 6) ? (i + 1) : i;
            const int tn  = (tbase + inx) * 4 + wave;
            const unsigned short* shrow = sh_ws + ((size_t)(bb * T_ + tn)) * H_;
            #pragma unroll
            for (int ks = 0; ks < 3; ks++)
                shn[ks] = *(const bf16x8*)(shrow + ks * 32 + q * 8);
        }

        // ---- epilogue: bias + log_softmax; one output row (u = u0+n) per lane
        #pragma unroll
        for (int nt = 0; nt < 8; nt++) {
            const f32x4 bias4 = *(const f32x4*)(b_out + nt * 16 + q * 4);
            acc[nt] += bias4;
        }

        float mx[8];
        #pragma unroll
        for (int nt = 0; nt < 8; nt++)
            mx[nt] = fmaxf(fmaxf(acc[nt][0], acc[nt][1]),
                           fmaxf(acc[nt][2], acc[nt][3]));
        float m = fmaxf(fmaxf(fmaxf(mx[0], mx[1]), fmaxf(mx[2], mx[3])),
                        fmaxf(fmaxf(mx[4], mx[5]), fmaxf(mx[6], mx[7])));
        m = fmaxf(m, __shfl_xor(m, 16, 64));
        m = fmaxf(m, __shfl_xor(m, 32, 64));

        float s0 = 0.f, s1 = 0.f, s2 = 0.f, s3 = 0.f;
        #pragma unroll
        for (int nt = 0; nt < 8; nt++) {
            s0 += __expf(acc[nt][0] - m);
            s1 += __expf(acc[nt][1] - m);
            s2 += __expf(acc[nt][2] - m);
            s3 += __expf(acc[nt][3] - m);
        }
        float ssum = (s0 + s1) + (s2 + s3);
        ssum += __shfl_xor(ssum, 16, 64);
        ssum += __shfl_xor(ssum, 32, 64);

        const float logz = m + __logf(ssum);

        // ---- per-wave private transpose, two half-passes (no barriers) ----
        // write chunk L = n*16 + w4*4 + q, phys P = L ^ ((L>>4)&7): conflict-free.
        // read  chunk c = ii*64 + lane, same swizzle: <=2-way.
        const size_t orow0 = (size_t)(bb * T_ + t) * U_ + u0;
        #pragma unroll
        for (int p = 0; p < 2; p++) {
            #pragma unroll
            for (int w4 = 0; w4 < 4; w4++) {
                const int nt = p * 4 + w4;
                const int L  = (n << 4) + (w4 << 2) + q;
                const int P  = L ^ ((L >> 4) & 7);
                Olw[P] = acc[nt] - logz;
            }
            #pragma unroll
            for (int ii = 0; ii < 4; ii++) {
                const int c = (ii << 6) + lane;
                const int P = c ^ ((c >> 4) & 7);
                const f32x4 v = Olw[P];
                const int u = c >> 4;      // 0..15
                const int j = c & 15;      // v-chunk within half
                *(f32x4*)(out + (orow0 + u) * V_ + p * 64 + j * 4) = v;
            }
        }

        // rotate prefetched shf
        #pragma unroll
        for (int ks = 0; ks < 3; ks++) shf[ks] = shn[ks];
    }
}

extern "C" void kernel_launch(void* const* d_in, const int* in_sizes, int n_in,
                              void* d_out, int out_size, void* d_ws, size_t ws_size,
                              hipStream_t stream)
{
    const float* s     = (const float*)d_in[0];
    const float* b     = (const float*)d_in[1];
    const float* W_sh  = (const float*)d_in[2];
    const float* b_sh  = (const float*)d_in[3];
    const float* W_bh  = (const float*)d_in[4];
    const float* b_bh  = (const float*)d_in[5];
    const float* W_out = (const float*)d_in[6];
    const float* b_out = (const float*)d_in[7];
    float* out = (float*)d_out;

    unsigned short* sh_ws  = (unsigned short*)d_ws;
    unsigned short* rbh_ws = sh_ws + (size_t)B_ * T_ * H_;    // +344064 B
    unsigned short* w_ws   = rbh_ws + (size_t)B_ * U_ * H_;   // +344064 B (16B aligned)

    prep_kernel<<<2 * B_ * T_ + 12, 128, 0, stream>>>(
        s, b, W_sh, b_sh, W_bh, b_bh, W_out, sh_ws, rbh_ws, w_ws);

    joiner_kernel<<<dim3(28 * 64), 256, 0, stream>>>(
        sh_ws, rbh_ws, w_ws, b_out, out);
}

// Round 12
// 419.418 us; speedup vs baseline: 1.4343x; 1.0391x over previous
//
#include <hip/hip_runtime.h>

#define B_ 4
#define T_ 448
#define U_ 448
#define SKS_ 96
#define BKS_ 32
#define H_ 96
#define V_ 128

typedef __attribute__((ext_vector_type(8))) short bf16x8;
typedef __attribute__((ext_vector_type(4))) float f32x4;
typedef __attribute__((ext_vector_type(4))) int i32x4;

__device__ __forceinline__ unsigned short f2bf(float f) {
    unsigned int u = __float_as_uint(f);
    u += 0x7fffu + ((u >> 16) & 1u);   // round-to-nearest-even
    return (unsigned short)(u >> 16);
}
__device__ __forceinline__ float bf2f(unsigned short h) {
    return __uint_as_float(((unsigned int)h) << 16);
}

// ---------------------------------------------------------------------------
// Prep kernel (unchanged):
//   blocks [0, B*T)        : sh[b,t,h] = s[b,t,:] . W_sh[h,:] + b_sh[h]        -> bf16 ws
//   blocks [B*T, 2*B*T)    : rbh[b,u,h] = relu(b[b,u,:] . W_bh[h,:] + b_bh[h]) -> bf16 ws
//   blocks [2*B*T, +12)    : repack W_out (f32 [128][96]) -> bf16 ws [k8][n][8]
// ---------------------------------------------------------------------------
__global__ __launch_bounds__(128) void prep_kernel(
    const float* __restrict__ s, const float* __restrict__ b,
    const float* __restrict__ W_sh, const float* __restrict__ b_sh,
    const float* __restrict__ W_bh, const float* __restrict__ b_bh,
    const float* __restrict__ W_out,
    unsigned short* __restrict__ sh_ws,
    unsigned short* __restrict__ rbh_ws,
    unsigned short* __restrict__ w_ws)
{
    const int blk = blockIdx.x;
    const int tid = threadIdx.x;

    if (blk < B_ * T_) {
        __shared__ float row[SKS_];
        if (tid < SKS_) row[tid] = s[(size_t)blk * SKS_ + tid];
        __syncthreads();
        if (tid < H_) {
            const float* w = W_sh + (size_t)tid * SKS_;
            float acc = b_sh[tid];
            #pragma unroll
            for (int k = 0; k < SKS_; k += 4) {
                acc += row[k] * w[k] + row[k + 1] * w[k + 1]
                     + row[k + 2] * w[k + 2] + row[k + 3] * w[k + 3];
            }
            sh_ws[(size_t)blk * H_ + tid] = f2bf(acc);
        }
    } else if (blk < 2 * B_ * T_) {
        const int r = blk - B_ * T_;
        __shared__ float row2[BKS_];
        if (tid < BKS_) row2[tid] = b[(size_t)r * BKS_ + tid];
        __syncthreads();
        if (tid < H_) {
            const float* w = W_bh + (size_t)tid * BKS_;
            float acc = b_bh[tid];
            #pragma unroll
            for (int k = 0; k < BKS_; k += 4) {
                acc += row2[k] * w[k] + row2[k + 1] * w[k + 1]
                     + row2[k + 2] * w[k + 2] + row2[k + 3] * w[k + 3];
            }
            acc = fmaxf(acc, 0.0f);
            rbh_ws[(size_t)r * H_ + tid] = f2bf(acc);
        }
    } else {
        // W_out repack: c = k8*128 + n ; src = W_out[n][k8*8 .. +8] ; dst 16B chunk c
        const int c = (blk - 2 * B_ * T_) * 128 + tid;   // 0..1535
        const int k8 = c >> 7;
        const int n  = c & 127;
        const float* src = W_out + (size_t)n * H_ + k8 * 8;
        unsigned short tmp[8];
        #pragma unroll
        for (int j = 0; j < 8; j++) tmp[j] = f2bf(src[j]);
        i32x4 v;
        v.x = (int)((unsigned)tmp[0] | ((unsigned)tmp[1] << 16));
        v.y = (int)((unsigned)tmp[2] | ((unsigned)tmp[3] << 16));
        v.z = (int)((unsigned)tmp[4] | ((unsigned)tmp[5] << 16));
        v.w = (int)((unsigned)tmp[6] | ((unsigned)tmp[7] << 16));
        ((i32x4*)w_ws)[c] = v;
    }
}

// ---------------------------------------------------------------------------
// Main kernel: EXACT R6 structure (best measured: 422.5 us) with ONE change:
// the final contiguous 1-KB wave stores are NONTEMPORAL.
// Theory: L2 write-allocate fetches each output line on store miss (~400 MB
// of useless FETCH, the residual in R7's counters). NT on fully-contiguous
// stores skips allocation -> output stream costs 411 MB instead of ~822 MB.
// (R2's NT regression was on scattered 64-B segments - different regime.)
// ---------------------------------------------------------------------------
__global__ __launch_bounds__(256) void joiner_kernel(
    const unsigned short* __restrict__ sh_ws,
    const unsigned short* __restrict__ rbh_ws,
    const unsigned short* __restrict__ w_ws,
    const float* __restrict__ b_out,
    float* __restrict__ out)
{
    __shared__ __align__(16) unsigned char SMEM[32768];   // 32 KB
    unsigned short* Wl = (unsigned short*)SMEM;           // [12*128*8] = 24 KB
    unsigned short* Al = (unsigned short*)(SMEM + 24576); //  [12*16*8] =  3 KB
    f32x4* Ol4 = (f32x4*)SMEM;                            // aliased after barrier

    const int tid = threadIdx.x;
    const int u0  = blockIdx.x * 16;
    const int t0  = blockIdx.y * 4;
    const int bb  = blockIdx.z;

    // ---- stage W_out fragments (contiguous 16B chunks, conflict-free) ----
    {
        const i32x4* src = (const i32x4*)w_ws;
        i32x4* dst = (i32x4*)Wl;
        #pragma unroll
        for (int i = 0; i < 6; i++) {
            const int c = i * 256 + tid;
            dst[c] = src[c];
        }
    }
    // ---- stage rbh tile: chunk tid = k8*16 + u  ->  LDS sequential ----
    if (tid < 192) {
        const int u  = tid & 15;
        const int k8 = tid >> 4;
        const i32x4* src = (const i32x4*)(rbh_ws +
            ((size_t)(bb * U_ + u0 + u)) * H_ + k8 * 8);
        ((i32x4*)Al)[tid] = *src;
    }
    __syncthreads();

    const int wave = tid >> 6;
    const int lane = tid & 63;
    const int t    = t0 + wave;
    const int n    = lane & 15;   // u-within-tile (output col); also v_local for W frag
    const int q    = lane >> 4;   // k-chunk; also v-subquad of output row index

    // sh fragments (global, L2-resident, uniform per quad)
    const unsigned short* shrow = sh_ws + ((size_t)(bb * T_ + t)) * H_;
    bf16x8 shf[3];
    #pragma unroll
    for (int ks = 0; ks < 3; ks++)
        shf[ks] = *(const bf16x8*)(shrow + ks * 32 + q * 8);

    f32x4 acc[8];
    #pragma unroll
    for (int nt = 0; nt < 8; nt++) acc[nt] = (f32x4){0.f, 0.f, 0.f, 0.f};

    #pragma unroll
    for (int ks = 0; ks < 3; ks++) {
        // z fragment: lane-sequential 16B read, z = sh * rbh in f32, back to bf16
        const bf16x8 rb = *(const bf16x8*)(Al + (ks * 64 + lane) * 8);
        bf16x8 af;
        #pragma unroll
        for (int j = 0; j < 8; j++) {
            const float z = bf2f((unsigned short)shf[ks][j]) *
                            bf2f((unsigned short)rb[j]);
            af[j] = (short)f2bf(z);
        }
        #pragma unroll
        for (int nt = 0; nt < 8; nt++) {
            const bf16x8 wfr = *(const bf16x8*)(Wl +
                ((size_t)((ks * 4 + q) * 128 + nt * 16 + n)) * 8);
            // A = W tile (M = v), B = z tile (N = u)
            acc[nt] = __builtin_amdgcn_mfma_f32_16x16x32_bf16(wfr, af, acc[nt], 0, 0, 0);
        }
    }

    // ---- epilogue: bias + log_softmax; one output row (u = u0+n) per lane ----
    #pragma unroll
    for (int nt = 0; nt < 8; nt++) {
        const f32x4 bias4 = *(const f32x4*)(b_out + nt * 16 + q * 4);
        acc[nt] += bias4;
    }

    float mx[8];
    #pragma unroll
    for (int nt = 0; nt < 8; nt++)
        mx[nt] = fmaxf(fmaxf(acc[nt][0], acc[nt][1]),
                       fmaxf(acc[nt][2], acc[nt][3]));
    float m = fmaxf(fmaxf(fmaxf(mx[0], mx[1]), fmaxf(mx[2], mx[3])),
                    fmaxf(fmaxf(mx[4], mx[5]), fmaxf(mx[6], mx[7])));
    m = fmaxf(m, __shfl_xor(m, 16, 64));
    m = fmaxf(m, __shfl_xor(m, 32, 64));

    float s0 = 0.f, s1 = 0.f, s2 = 0.f, s3 = 0.f;
    #pragma unroll
    for (int nt = 0; nt < 8; nt++) {
        s0 += __expf(acc[nt][0] - m);
        s1 += __expf(acc[nt][1] - m);
        s2 += __expf(acc[nt][2] - m);
        s3 += __expf(acc[nt][3] - m);
    }
    float ssum = (s0 + s1) + (s2 + s3);
    ssum += __shfl_xor(ssum, 16, 64);
    ssum += __shfl_xor(ssum, 32, 64);

    const float logz = m + __logf(ssum);

    // ---- LDS-transpose store path ----
    // Wait until all waves are done reading Wl/Al, then alias as output buffer.
    __syncthreads();

    // write: logical 16B-chunk index L = wave*512 + n*32 + nt*4 + q
    //        phys = L ^ ((L>>5)&7)  (row-XOR swizzle, <=2-way conflict)
    #pragma unroll
    for (int nt = 0; nt < 8; nt++) {
        const int L = (wave << 9) + (n << 5) + (nt << 2) + q;
        const int P = L ^ ((L >> 5) & 7);
        Ol4[P] = acc[nt] - logz;
    }

    // read linear + contiguous 1-KB wave stores (16 rows x 512 B per wave),
    // NONTEMPORAL: skip L2 line allocation on the 411-MB output stream.
    const size_t obase = (((size_t)(bb * T_ + t)) * U_ + u0) * V_;
    #pragma unroll
    for (int i = 0; i < 8; i++) {
        const int L = (wave << 9) + (i << 6) + lane;
        const int P = L ^ ((L >> 5) & 7);
        const f32x4 v = Ol4[P];
        __builtin_nontemporal_store(v,
            (f32x4*)(out + obase + (size_t)((i << 6) + lane) * 4));
    }
}

extern "C" void kernel_launch(void* const* d_in, const int* in_sizes, int n_in,
                              void* d_out, int out_size, void* d_ws, size_t ws_size,
                              hipStream_t stream)
{
    const float* s     = (const float*)d_in[0];
    const float* b     = (const float*)d_in[1];
    const float* W_sh  = (const float*)d_in[2];
    const float* b_sh  = (const float*)d_in[3];
    const float* W_bh  = (const float*)d_in[4];
    const float* b_bh  = (const float*)d_in[5];
    const float* W_out = (const float*)d_in[6];
    const float* b_out = (const float*)d_in[7];
    float* out = (float*)d_out;

    unsigned short* sh_ws  = (unsigned short*)d_ws;
    unsigned short* rbh_ws = sh_ws + (size_t)B_ * T_ * H_;    // +344064 B
    unsigned short* w_ws   = rbh_ws + (size_t)B_ * U_ * H_;   // +344064 B (16B aligned)

    prep_kernel<<<2 * B_ * T_ + 12, 128, 0, stream>>>(
        s, b, W_sh, b_sh, W_bh, b_bh, W_out, sh_ws, rbh_ws, w_ws);

    joiner_kernel<<<dim3(U_ / 16, T_ / 4, B_), 256, 0, stream>>>(
        sh_ws, rbh_ws, w_ws, b_out, out);
}